// Round 7
// baseline (306.040 us; speedup 1.0000x reference)
//
#include <hip/hip_runtime.h>
#include <hip/hip_bf16.h>

// Capsule routing; u_hat never materialized. Per iter:
//   vjt: vj = S@W_o -> global sumsq; t = W_o@vj (UNNORMALIZED)
//   route: bb = (t.u^T)/nrm -> softmax_o -> S' += Wv.u   (MFMA 16x16x32 bf16)
// k_route v3: n-tile 32, 1024 blocks, 3 blocks/CU. u staged ONCE, TRANSPOSED
// (uT[k][n] bf16) so phase-2 B-frags are single ds_read_b128. t A-frags come
// straight from global (L2-hot) -> phase 1 needs no barriers at all.

constexpr int B = 32, N = 1024, K = 512, O = 32, D = 64, F = 2048;
constexpr int STT = 36;  // uT row stride (u16): 72B -> 18dw, bank-spread rows

typedef __attribute__((ext_vector_type(8))) short bf16x8;
typedef __attribute__((ext_vector_type(4))) float f32x4;

__device__ inline unsigned int pk_hi(float x, float y) {
  union { __hip_bfloat162 h; unsigned int u; } c;
  c.h = __float22bfloat162_rn(float2{x, y});
  return c.u;
}
__device__ inline unsigned short bf16_1(float x) {
  return (unsigned short)(pk_hi(x, 0.f) & 0xffffu);
}
__device__ inline void split2(float x, unsigned short& h, unsigned short& l) {
  h = bf16_1(x);
  l = bf16_1(x - __uint_as_float((unsigned int)h << 16));
}

// colsum[b,k] = (1/32) sum_n u[b,n,k]  (iter-0: softmax(0) uniform)
__global__ __launch_bounds__(256) void k_colsum(const float* __restrict__ u,
                                                float* __restrict__ cs) {
  int b = blockIdx.x, n0 = blockIdx.y * 32;
  int kq = (threadIdx.x & 127) * 4, ng = threadIdx.x >> 7;
  const float* ub = u + ((size_t)b * N + n0 + ng * 16) * K + kq;
  float4 a = {0.f, 0.f, 0.f, 0.f};
#pragma unroll
  for (int r = 0; r < 16; r++) {
    float4 v = *(const float4*)&ub[(size_t)r * K];
    a.x += v.x; a.y += v.y; a.z += v.z; a.w += v.w;
  }
  __shared__ float4 red[128];
  if (ng) red[threadIdx.x & 127] = a;
  __syncthreads();
  if (!ng) {
    float4 o = red[threadIdx.x];
    atomicAdd(&cs[b * K + kq + 0], (a.x + o.x) * (1.f / 32.f));
    atomicAdd(&cs[b * K + kq + 1], (a.y + o.y) * (1.f / 32.f));
    atomicAdd(&cs[b * K + kq + 2], (a.z + o.z) * (1.f / 32.f));
    atomicAdd(&cs[b * K + kq + 3], (a.w + o.w) * (1.f / 32.f));
  }
}

// vj[d]=sum_k s[k]W[k,o*64+d] -> sumsq atomic; t[k]=sum_d vj[d]W[k,o*64+d].
__global__ __launch_bounds__(512) void k_vjt(const float* __restrict__ S,
                                             const float* __restrict__ colsum,
                                             const float* __restrict__ W,
                                             float* __restrict__ sumsq, int slot,
                                             float* __restrict__ t) {
  __shared__ __align__(16) float s_s[K];
  __shared__ float red[7][D];
  __shared__ __align__(16) float vs[D];
  int bo = blockIdx.x, b = bo >> 5, o = bo & 31;
  int d = threadIdx.x & 63, ks = threadIdx.x >> 6;  // 8-way k split
  const float* src = (slot == 0) ? (colsum + (size_t)b * K) : (S + (size_t)bo * K);
  for (int i = threadIdx.x; i < K; i += 512) s_s[i] = src[i];
  __syncthreads();
  float acc = 0.f;
  const float* Wc = W + (size_t)o * D + d;
  for (int k = ks * 64; k < ks * 64 + 64; k += 4) {
    acc += s_s[k] * Wc[(size_t)k * F] + s_s[k + 1] * Wc[(size_t)(k + 1) * F] +
           s_s[k + 2] * Wc[(size_t)(k + 2) * F] + s_s[k + 3] * Wc[(size_t)(k + 3) * F];
  }
  if (ks) red[ks - 1][d] = acc;
  __syncthreads();
  if (ks == 0) {
#pragma unroll
    for (int j = 0; j < 7; j++) acc += red[j][d];
    vs[d] = acc;
    float ss = acc * acc;
#pragma unroll
    for (int m = 32; m >= 1; m >>= 1) ss += __shfl_xor(ss, m, 64);
    if (d == 0) atomicAdd(&sumsq[slot], ss);
  }
  __syncthreads();
  {  // t phase: wave handles 64 rows, 8 lanes/row (coalesced)
    int wave = threadIdx.x >> 6, lane = threadIdx.x & 63;
    int rr = lane >> 3, dc = lane & 7;
    float4 va = *(const float4*)&vs[dc * 8];
    float4 vb = *(const float4*)&vs[dc * 8 + 4];
#pragma unroll
    for (int i = 0; i < 8; i++) {
      int kk = wave * 64 + i * 8 + rr;
      const float* Wr = W + (size_t)kk * F + o * 64 + dc * 8;
      float4 wa = *(const float4*)Wr;
      float4 wb = *(const float4*)(Wr + 4);
      float p = wa.x * va.x + wa.y * va.y + wa.z * va.z + wa.w * va.w +
                wb.x * vb.x + wb.y * vb.y + wb.z * vb.z + wb.w * vb.w;
      p += __shfl_xor(p, 1, 64);
      p += __shfl_xor(p, 2, 64);
      p += __shfl_xor(p, 4, 64);
      if (dc == 0) t[(size_t)bo * K + kk] = p;
    }
  }
}

// Final: vj from S row -> squash -> out
__global__ __launch_bounds__(512) void k_out(const float* __restrict__ S,
                                             const float* __restrict__ W,
                                             float* __restrict__ out) {
  __shared__ __align__(16) float s_s[K];
  __shared__ float red[7][D];
  int bo = blockIdx.x, o = bo & 31;
  int d = threadIdx.x & 63, ks = threadIdx.x >> 6;
  const float* src = S + (size_t)bo * K;
  for (int i = threadIdx.x; i < K; i += 512) s_s[i] = src[i];
  __syncthreads();
  float acc = 0.f;
  const float* Wc = W + (size_t)o * D + d;
  for (int k = ks * 64; k < ks * 64 + 64; k += 4) {
    acc += s_s[k] * Wc[(size_t)k * F] + s_s[k + 1] * Wc[(size_t)(k + 1) * F] +
           s_s[k + 2] * Wc[(size_t)(k + 2) * F] + s_s[k + 3] * Wc[(size_t)(k + 3) * F];
  }
  if (ks) red[ks - 1][d] = acc;
  __syncthreads();
  if (ks == 0) {
#pragma unroll
    for (int j = 0; j < 7; j++) acc += red[j][d];
    float ss = acc * acc;
#pragma unroll
    for (int m = 32; m >= 1; m >>= 1) ss += __shfl_xor(ss, m, 64);
    float s = ss + 1e-7f;
    out[(size_t)bo * D + d] = (sqrtf(s) / (0.5f + s)) * acc;
  }
}

// Fused routing step, 32-n tile, 256 thr (4 waves), 3 blocks/CU, grid 1024.
__global__ __launch_bounds__(256, 3) void k_route(const float* __restrict__ t,
                                                  const float* __restrict__ u,
                                                  const float* __restrict__ sumsq,
                                                  int slot, float* __restrict__ S) {
  __shared__ unsigned short uT[K * STT];    // 36864 B: uT[k][n] bf16 of u[n][k]
  __shared__ unsigned short wvh[O * STT];   // 2304 B
  __shared__ unsigned short wvl[O * STT];   // 2304 B
  __shared__ float wv[O * STT];             // 4608 B (logits / exp scratch)
  __shared__ float psum[8 * STT];           // 1152 B (partial max, then sums)
  __shared__ float mbuf[STT];               // col max then unused

  const int b = blockIdx.x, n0 = blockIdx.y * 32;
  const int tid = threadIdx.x, lane = tid & 63, wave = tid >> 6;
  const int m = lane & 15, oct = lane >> 4;
  const float* ub = u + ((size_t)b * N + n0) * K;
  const float* tb = t + (size_t)b * O * K;
  const float nrm_inv = rsqrtf(fmaxf(sumsq[slot], 1e-12f));

  // ---- stage uT: 32 n-rows x 512 k, transposed, bf16 hi ----
#pragma unroll
  for (int h = 0; h < 16; h++) {
    int i = tid + h * 256;        // 4096 float4 slots
    int r = i & 31;               // n
    int kb4 = (i >> 5) * 4;       // k
    float4 v = *(const float4*)&ub[(size_t)r * K + kb4];
    uT[(kb4 + 0) * STT + r] = bf16_1(v.x);
    uT[(kb4 + 1) * STT + r] = bf16_1(v.y);
    uT[(kb4 + 2) * STT + r] = bf16_1(v.z);
    uT[(kb4 + 3) * STT + r] = bf16_1(v.w);
  }
  __syncthreads();

  // ---- phase 1: bb[32o][32n] = t . u^T  (t from global, barrier-free) ----
  const int mo = wave & 1, nt = (wave >> 1) & 1;
  const float* trow = tb + (size_t)(mo * 16 + m) * K;
  f32x4 accb = {0.f, 0.f, 0.f, 0.f};
  for (int kc = 0; kc < K; kc += 32) {
    int kb = kc + oct * 8;
    float4 t0 = *(const float4*)&trow[kb];
    float4 t1 = *(const float4*)&trow[kb + 4];
    bf16x8 ah, al;
    unsigned short h, l;
    split2(t0.x, h, l); ah[0] = (short)h; al[0] = (short)l;
    split2(t0.y, h, l); ah[1] = (short)h; al[1] = (short)l;
    split2(t0.z, h, l); ah[2] = (short)h; al[2] = (short)l;
    split2(t0.w, h, l); ah[3] = (short)h; al[3] = (short)l;
    split2(t1.x, h, l); ah[4] = (short)h; al[4] = (short)l;
    split2(t1.y, h, l); ah[5] = (short)h; al[5] = (short)l;
    split2(t1.z, h, l); ah[6] = (short)h; al[6] = (short)l;
    split2(t1.w, h, l); ah[7] = (short)h; al[7] = (short)l;
    bf16x8 bh;
#pragma unroll
    for (int j = 0; j < 8; j++) bh[j] = (short)uT[(kb + j) * STT + nt * 16 + m];
    accb = __builtin_amdgcn_mfma_f32_16x16x32_bf16(ah, bh, accb, 0, 0, 0);
    accb = __builtin_amdgcn_mfma_f32_16x16x32_bf16(al, bh, accb, 0, 0, 0);
  }
#pragma unroll
  for (int r = 0; r < 4; r++)  // D: col=m (n), row=oct*4+r (o)
    wv[(mo * 16 + oct * 4 + r) * STT + nt * 16 + m] = accb[r] * nrm_inv;
  __syncthreads();

  // ---- softmax over o, fully parallel: n=tid&31, g=tid>>5 owns 4 o's ----
  {
    int n = tid & 31, g = tid >> 5;
    float m4 = -1e30f;
#pragma unroll
    for (int j = 0; j < 4; j++) m4 = fmaxf(m4, wv[(g * 4 + j) * STT + n]);
    psum[g * STT + n] = m4;
    __syncthreads();
    if (tid < 32) {
      float mx = psum[tid];
#pragma unroll
      for (int gg = 1; gg < 8; gg++) mx = fmaxf(mx, psum[gg * STT + tid]);
      mbuf[tid] = mx;
    }
    __syncthreads();
    float mx = mbuf[n];
    float s4 = 0.f;
#pragma unroll
    for (int j = 0; j < 4; j++) {
      float e = __expf(wv[(g * 4 + j) * STT + n] - mx);
      wv[(g * 4 + j) * STT + n] = e;
      s4 += e;
    }
    psum[g * STT + n] = s4;
    __syncthreads();
    if (tid < 32) {
      float s = 0.f;
#pragma unroll
      for (int gg = 0; gg < 8; gg++) s += psum[gg * STT + tid];
      mbuf[tid] = 1.f / s;
    }
    __syncthreads();
    float inv = mbuf[n];
#pragma unroll
    for (int j = 0; j < 4; j++) {
      unsigned short h, l;
      split2(wv[(g * 4 + j) * STT + n] * inv, h, l);
      wvh[(g * 4 + j) * STT + n] = h;
      wvl[(g * 4 + j) * STT + n] = l;
    }
  }
  __syncthreads();

  // ---- phase 2: S += Wv . u  (kred = n = 32, one MFMA step; B from uT rows) ----
  const int mo2 = wave & 1, kg = (wave >> 1) & 1;
  const int o0 = mo2 * 16;
  bf16x8 a2h = *(const bf16x8*)&wvh[(o0 + m) * STT + oct * 8];
  bf16x8 a2l = *(const bf16x8*)&wvl[(o0 + m) * STT + oct * 8];
  float* Sb = S + (size_t)b * O * K;
#pragma unroll 2
  for (int it = 0; it < 16; it++) {
    int kcol = it * 32 + kg * 16 + m;
    bf16x8 b2 = *(const bf16x8*)&uT[kcol * STT + oct * 8];
    f32x4 acs = {0.f, 0.f, 0.f, 0.f};
    acs = __builtin_amdgcn_mfma_f32_16x16x32_bf16(a2h, b2, acs, 0, 0, 0);
    acs = __builtin_amdgcn_mfma_f32_16x16x32_bf16(a2l, b2, acs, 0, 0, 0);
#pragma unroll
    for (int r = 0; r < 4; r++)  // D: col=m -> kcol, row=oct*4+r -> o
      atomicAdd(&Sb[(size_t)(o0 + oct * 4 + r) * K + kcol], acs[r]);
  }
}

extern "C" void kernel_launch(void* const* d_in, const int* in_sizes, int n_in,
                              void* d_out, int out_size, void* d_ws, size_t ws_size,
                              hipStream_t stream) {
  const float* u = (const float*)d_in[0];  // [B,N,K] f32
  const float* W = (const float*)d_in[1];  // [K,F] f32
  float* out = (float*)d_out;              // [B,O,D] f32

  float* ws = (float*)d_ws;
  float* S1 = ws;                           // B*O*K
  float* S2 = S1 + (size_t)B * O * K;       // B*O*K
  float* colsum = S2 + (size_t)B * O * K;   // B*K
  float* sumsq = colsum + (size_t)B * K;    // 16 (2 used)
  float* t = sumsq + 16;                    // B*O*K

  hipMemsetAsync(S1, 0, ((size_t)2 * B * O * K + B * K + 16) * sizeof(float), stream);

  k_colsum<<<dim3(B, 32), 256, 0, stream>>>(u, colsum);
  k_vjt<<<B * O, 512, 0, stream>>>(S1, colsum, W, sumsq, 0, t);   // iter0 (uniform)
  k_route<<<dim3(B, N / 32), 256, 0, stream>>>(t, u, sumsq, 0, S1);
  k_vjt<<<B * O, 512, 0, stream>>>(S1, colsum, W, sumsq, 1, t);   // iter1
  k_route<<<dim3(B, N / 32), 256, 0, stream>>>(t, u, sumsq, 1, S2);
  k_out<<<B * O, 512, 0, stream>>>(S2, W, out);                   // iter2 + squash
}

// Round 8
// 215.258 us; speedup vs baseline: 1.4217x; 1.4217x over previous
//
#include <hip/hip_runtime.h>
#include <hip/hip_bf16.h>

// Capsule routing; u_hat never materialized. Per iter:
//   vjt: vj = S@W_o -> global sumsq; t = W_o@vj (UNNORMALIZED)
//   route: bb = (t.u^T)/nrm -> softmax_o -> Spart[nt] = Wv.u  (MFMA bf16 hi/lo)
// v5: n-tile 32, 256thr, 1024 blocks (~4-8 blocks/CU). NO atomics: each block
// writes its own partial-S slab; k_vjt/k_out sum the 32 slabs on load.

constexpr int B = 32, N = 1024, K = 512, O = 32, D = 64, F = 2048;
constexpr int NT = 32;   // n-tile -> 32 slabs per b
constexpr int ST = 72;   // LDS u16 row stride: 144B, 16B-aligned, b128-friendly

typedef __attribute__((ext_vector_type(8))) short bf16x8;
typedef __attribute__((ext_vector_type(4))) float f32x4;

__device__ inline unsigned int pk_hi(float x, float y) {
  union { __hip_bfloat162 h; unsigned int u; } c;
  c.h = __float22bfloat162_rn(float2{x, y});
  return c.u;
}
__device__ inline unsigned short bf16_1(float x) {
  return (unsigned short)(pk_hi(x, 0.f) & 0xffffu);
}
__device__ inline void split2(float x, unsigned short& h, unsigned short& l) {
  h = bf16_1(x);
  l = bf16_1(x - __uint_as_float((unsigned int)h << 16));
}
__device__ inline int swz(int r) { return ((r >> 3) & 7) << 3; }

__device__ inline void stage_hi(unsigned short* hi, int r, int c4, float4 v) {
  int c = c4 ^ swz(r);
  uint2 p;
  p.x = pk_hi(v.x, v.y);
  p.y = pk_hi(v.z, v.w);
  *(uint2*)&hi[r * ST + c] = p;
}
__device__ inline void stage_hilo(unsigned short* hi, unsigned short* lo, int r,
                                  int c4, float4 v) {
  int c = c4 ^ swz(r);
  uint2 ph, pl;
  ph.x = pk_hi(v.x, v.y);
  ph.y = pk_hi(v.z, v.w);
  pl.x = pk_hi(v.x - __uint_as_float(ph.x << 16),
               v.y - __uint_as_float(ph.x & 0xffff0000u));
  pl.y = pk_hi(v.z - __uint_as_float(ph.y << 16),
               v.w - __uint_as_float(ph.y & 0xffff0000u));
  *(uint2*)&hi[r * ST + c] = ph;
  *(uint2*)&lo[r * ST + c] = pl;
}
__device__ inline bf16x8 frag_row(const unsigned short* p, int r, int k0) {
  return *(const bf16x8*)&p[r * ST + (k0 ^ swz(r))];
}
__device__ inline bf16x8 frag_col(const unsigned short* p, int c, int n0) {
  bf16x8 f;
#pragma unroll
  for (int j = 0; j < 8; j++) {
    int n = n0 + j;
    f[j] = (short)p[n * ST + (c ^ swz(n))];
  }
  return f;
}

// colsum[b,k] = (1/32) sum_n u[b,n,k]  (iter-0: softmax(0) uniform)
__global__ __launch_bounds__(256) void k_colsum(const float* __restrict__ u,
                                                float* __restrict__ cs) {
  int b = blockIdx.x, n0 = blockIdx.y * 32;
  int kq = (threadIdx.x & 127) * 4, ng = threadIdx.x >> 7;
  const float* ub = u + ((size_t)b * N + n0 + ng * 16) * K + kq;
  float4 a = {0.f, 0.f, 0.f, 0.f};
#pragma unroll
  for (int r = 0; r < 16; r++) {
    float4 v = *(const float4*)&ub[(size_t)r * K];
    a.x += v.x; a.y += v.y; a.z += v.z; a.w += v.w;
  }
  __shared__ float4 red[128];
  if (ng) red[threadIdx.x & 127] = a;
  __syncthreads();
  if (!ng) {
    float4 o = red[threadIdx.x];
    atomicAdd(&cs[b * K + kq + 0], (a.x + o.x) * (1.f / 32.f));
    atomicAdd(&cs[b * K + kq + 1], (a.y + o.y) * (1.f / 32.f));
    atomicAdd(&cs[b * K + kq + 2], (a.z + o.z) * (1.f / 32.f));
    atomicAdd(&cs[b * K + kq + 3], (a.w + o.w) * (1.f / 32.f));
  }
}

// vj[d]=sum_k s[k]W[k,o*64+d] -> sumsq atomic; t[k]=sum_d vj[d]W[k,o*64+d].
// slot 0: s = colsum row; else s = sum of 32 partial-S slabs.
__global__ __launch_bounds__(512) void k_vjt(const float* __restrict__ Sp,
                                             const float* __restrict__ colsum,
                                             const float* __restrict__ W,
                                             float* __restrict__ sumsq, int slot,
                                             float* __restrict__ t) {
  __shared__ __align__(16) float s_s[K];
  __shared__ float red[7][D];
  __shared__ __align__(16) float vs[D];
  int bo = blockIdx.x, b = bo >> 5, o = bo & 31;
  int d = threadIdx.x & 63, ks = threadIdx.x >> 6;  // 8-way k split
  if (slot == 0) {
    for (int i = threadIdx.x; i < K; i += 512) s_s[i] = colsum[(size_t)b * K + i];
  } else {
    const float* base = Sp + ((size_t)b * NT * O + o) * K;
    int i = threadIdx.x;  // 512 threads, one k each
    float a = 0.f;
#pragma unroll
    for (int nt = 0; nt < NT; nt++) a += base[(size_t)nt * O * K + i];
    s_s[i] = a;
  }
  __syncthreads();
  float acc = 0.f;
  const float* Wc = W + (size_t)o * D + d;
  for (int k = ks * 64; k < ks * 64 + 64; k += 4) {
    acc += s_s[k] * Wc[(size_t)k * F] + s_s[k + 1] * Wc[(size_t)(k + 1) * F] +
           s_s[k + 2] * Wc[(size_t)(k + 2) * F] + s_s[k + 3] * Wc[(size_t)(k + 3) * F];
  }
  if (ks) red[ks - 1][d] = acc;
  __syncthreads();
  if (ks == 0) {
#pragma unroll
    for (int j = 0; j < 7; j++) acc += red[j][d];
    vs[d] = acc;
    float ss = acc * acc;
#pragma unroll
    for (int m = 32; m >= 1; m >>= 1) ss += __shfl_xor(ss, m, 64);
    if (d == 0) atomicAdd(&sumsq[slot], ss);
  }
  __syncthreads();
  {  // t phase: wave handles 64 rows, 8 lanes/row (coalesced)
    int wave = threadIdx.x >> 6, lane = threadIdx.x & 63;
    int rr = lane >> 3, dc = lane & 7;
    float4 va = *(const float4*)&vs[dc * 8];
    float4 vb = *(const float4*)&vs[dc * 8 + 4];
#pragma unroll
    for (int i = 0; i < 8; i++) {
      int kk = wave * 64 + i * 8 + rr;
      const float* Wr = W + (size_t)kk * F + o * 64 + dc * 8;
      float4 wa = *(const float4*)Wr;
      float4 wb = *(const float4*)(Wr + 4);
      float p = wa.x * va.x + wa.y * va.y + wa.z * va.z + wa.w * va.w +
                wb.x * vb.x + wb.y * vb.y + wb.z * vb.z + wb.w * vb.w;
      p += __shfl_xor(p, 1, 64);
      p += __shfl_xor(p, 2, 64);
      p += __shfl_xor(p, 4, 64);
      if (dc == 0) t[(size_t)bo * K + kk] = p;
    }
  }
}

// Final: vj from summed slabs -> squash -> out
__global__ __launch_bounds__(512) void k_out(const float* __restrict__ Sp,
                                             const float* __restrict__ W,
                                             float* __restrict__ out) {
  __shared__ __align__(16) float s_s[K];
  __shared__ float red[7][D];
  int bo = blockIdx.x, b = bo >> 5, o = bo & 31;
  int d = threadIdx.x & 63, ks = threadIdx.x >> 6;
  {
    const float* base = Sp + ((size_t)b * NT * O + o) * K;
    int i = threadIdx.x;
    float a = 0.f;
#pragma unroll
    for (int nt = 0; nt < NT; nt++) a += base[(size_t)nt * O * K + i];
    s_s[i] = a;
  }
  __syncthreads();
  float acc = 0.f;
  const float* Wc = W + (size_t)o * D + d;
  for (int k = ks * 64; k < ks * 64 + 64; k += 4) {
    acc += s_s[k] * Wc[(size_t)k * F] + s_s[k + 1] * Wc[(size_t)(k + 1) * F] +
           s_s[k + 2] * Wc[(size_t)(k + 2) * F] + s_s[k + 3] * Wc[(size_t)(k + 3) * F];
  }
  if (ks) red[ks - 1][d] = acc;
  __syncthreads();
  if (ks == 0) {
#pragma unroll
    for (int j = 0; j < 7; j++) acc += red[j][d];
    float ss = acc * acc;
#pragma unroll
    for (int m = 32; m >= 1; m >>= 1) ss += __shfl_xor(ss, m, 64);
    float s = ss + 1e-7f;
    out[(size_t)bo * D + d] = (sqrtf(s) / (0.5f + s)) * acc;
  }
}

// Fused routing step, 32-n tile, 256 thr (4 waves), grid (B,32)=1024 blocks.
// phase1: bb[32o][32n]=(t.u^T)/nrm (per-chunk LDS staging, b128 frags);
// softmax over o (parallel); phase2: Spart[b,nt] = Wv.u (frag_col B, plain stores)
__global__ __launch_bounds__(256, 4) void k_route(const float* __restrict__ t,
                                                  const float* __restrict__ u,
                                                  const float* __restrict__ sumsq,
                                                  int slot, float* __restrict__ Sp) {
  __shared__ unsigned short u_hi[32 * ST];                   // 4608 B
  __shared__ unsigned short t_hi[32 * ST], t_lo[32 * ST];    // 2x4608 B
  __shared__ float wv[32 * 36];                              // 4608 B logits
  __shared__ float psum[8 * 36];                             // softmax partials
  __shared__ float mbuf[36];
  unsigned short* wvh = t_hi;  // alias: t dead after phase 1
  unsigned short* wvl = t_lo;

  const int b = blockIdx.x, n0 = blockIdx.y * 32;
  const int tid = threadIdx.x, lane = tid & 63, wave = tid >> 6;
  const int m = lane & 15, oct = lane >> 4;
  const float* ub = u + ((size_t)b * N + n0) * K;
  const float* tb = t + (size_t)b * O * K;
  const float nrm_inv = rsqrtf(fmaxf(sumsq[slot], 1e-12f));

  // ---- phase 1: bb[32o][32n] = t . u^T ----
  const int mo = wave & 1, nt = wave >> 1;  // o-half, n-half (16x16 tiles)
  f32x4 accb = {0.f, 0.f, 0.f, 0.f};
  for (int kc = 0; kc < K; kc += 64) {
    __syncthreads();
#pragma unroll
    for (int h = 0; h < 2; h++) {  // t: 512 f4 hi/lo + u: 512 f4 hi, 2+2/thread
      int i = tid + h * 256;
      int r = i >> 4, c4 = (i & 15) * 4;
      stage_hilo(t_hi, t_lo, r, c4, *(const float4*)&tb[(size_t)r * K + kc + c4]);
      stage_hi(u_hi, r, c4, *(const float4*)&ub[(size_t)r * K + kc + c4]);
    }
    __syncthreads();
#pragma unroll
    for (int ks = 0; ks < 64; ks += 32) {
      bf16x8 ah = frag_row(t_hi, mo * 16 + m, ks + oct * 8);
      bf16x8 al = frag_row(t_lo, mo * 16 + m, ks + oct * 8);
      bf16x8 bh = frag_row(u_hi, nt * 16 + m, ks + oct * 8);
      accb = __builtin_amdgcn_mfma_f32_16x16x32_bf16(ah, bh, accb, 0, 0, 0);
      accb = __builtin_amdgcn_mfma_f32_16x16x32_bf16(al, bh, accb, 0, 0, 0);
    }
  }
  __syncthreads();
#pragma unroll
  for (int r = 0; r < 4; r++)  // D: col=m (n), row=oct*4+r (o)
    wv[(mo * 16 + oct * 4 + r) * 36 + nt * 16 + m] = accb[r] * nrm_inv;
  __syncthreads();

  // ---- softmax over o, parallel: n=tid&31, g=tid>>5 owns 4 o's ----
  {
    int n = tid & 31, g = tid >> 5;
    float m4 = -1e30f;
#pragma unroll
    for (int j = 0; j < 4; j++) m4 = fmaxf(m4, wv[(g * 4 + j) * 36 + n]);
    psum[g * 36 + n] = m4;
    __syncthreads();
    if (tid < 32) {
      float mx = psum[tid];
#pragma unroll
      for (int gg = 1; gg < 8; gg++) mx = fmaxf(mx, psum[gg * 36 + tid]);
      mbuf[tid] = mx;
    }
    __syncthreads();
    float mx = mbuf[n];
    float s4 = 0.f;
#pragma unroll
    for (int j = 0; j < 4; j++) {
      float e = __expf(wv[(g * 4 + j) * 36 + n] - mx);
      wv[(g * 4 + j) * 36 + n] = e;
      s4 += e;
    }
    psum[g * 36 + n] = s4;
    __syncthreads();
    if (tid < 32) {
      float s = 0.f;
#pragma unroll
      for (int gg = 0; gg < 8; gg++) s += psum[gg * 36 + tid];
      mbuf[tid] = 1.f / s;
    }
    __syncthreads();
    float inv = mbuf[n];
#pragma unroll
    for (int j = 0; j < 4; j++) {  // Wv -> bf16 hi/lo into dead t region
      unsigned short h, l;
      split2(wv[(g * 4 + j) * 36 + n] * inv, h, l);
      wvh[(g * 4 + j) * ST + n] = h;
      wvl[(g * 4 + j) * ST + n] = l;
    }
  }
  __syncthreads();

  // ---- phase 2: Spart = Wv . u  (kred = n = 32, plain stores, no atomics) ----
  const int mo2 = wave & 1, kp = wave >> 1;  // o-half, ktile-pair
  const int o0 = mo2 * 16;
  bf16x8 a_h = *(const bf16x8*)&wvh[(o0 + m) * ST + oct * 8];
  bf16x8 a_l = *(const bf16x8*)&wvl[(o0 + m) * ST + oct * 8];
  float* Sb = Sp + ((size_t)b * NT + blockIdx.y) * O * K;
  for (int kc = 0; kc < K; kc += 64) {
    __syncthreads();
#pragma unroll
    for (int h = 0; h < 2; h++) {  // restage u chunk (L2/L3-hot), hi only
      int i = tid + h * 256;
      int r = i >> 4, c4 = (i & 15) * 4;
      stage_hi(u_hi, r, c4, *(const float4*)&ub[(size_t)r * K + kc + c4]);
    }
    __syncthreads();
#pragma unroll
    for (int kt = kp * 2; kt < kp * 2 + 2; kt++) {
      int c = kt * 16 + m;  // column within chunk
      bf16x8 bh = frag_col(u_hi, c, oct * 8);
      f32x4 acs = {0.f, 0.f, 0.f, 0.f};
      acs = __builtin_amdgcn_mfma_f32_16x16x32_bf16(a_h, bh, acs, 0, 0, 0);
      acs = __builtin_amdgcn_mfma_f32_16x16x32_bf16(a_l, bh, acs, 0, 0, 0);
#pragma unroll
      for (int r = 0; r < 4; r++)  // D: col=m -> kcol, row=oct*4+r -> o
        Sb[(size_t)(o0 + oct * 4 + r) * K + kc + c] = acs[r];
    }
  }
}

extern "C" void kernel_launch(void* const* d_in, const int* in_sizes, int n_in,
                              void* d_out, int out_size, void* d_ws, size_t ws_size,
                              hipStream_t stream) {
  const float* u = (const float*)d_in[0];  // [B,N,K] f32
  const float* W = (const float*)d_in[1];  // [K,F] f32
  float* out = (float*)d_out;              // [B,O,D] f32

  float* ws = (float*)d_ws;
  float* Sp = ws;                               // B*NT*O*K = 16.78M fl (67MB)
  float* t = Sp + (size_t)B * NT * O * K;       // B*O*K (2MB)
  float* colsum = t + (size_t)B * O * K;        // B*K
  float* sumsq = colsum + (size_t)B * K;        // 16 (2 used)

  hipMemsetAsync(colsum, 0, ((size_t)B * K + 16) * sizeof(float), stream);

  k_colsum<<<dim3(B, 32), 256, 0, stream>>>(u, colsum);
  k_vjt<<<B * O, 512, 0, stream>>>(Sp, colsum, W, sumsq, 0, t);   // iter0 (uniform)
  k_route<<<dim3(B, NT), 256, 0, stream>>>(t, u, sumsq, 0, Sp);
  k_vjt<<<B * O, 512, 0, stream>>>(Sp, colsum, W, sumsq, 1, t);   // iter1
  k_route<<<dim3(B, NT), 256, 0, stream>>>(t, u, sumsq, 1, Sp);
  k_out<<<B * O, 512, 0, stream>>>(Sp, W, out);                   // iter2 + squash
}